// Round 1
// 324.800 us; speedup vs baseline: 1.0518x; 1.0518x over previous
//
#include <hip/hip_runtime.h>
#include <math.h>

// ConvKAN3D: 3x [conv3d(3x3x3,pad1) -> cubic KAN spline + SiLU -> BN(eval) -> maxpool 2x2x2]
// then global mean pool + fc1/relu/fc2.
// r11: BARRIER-FREE K-loop. Each wave owns a private double-buffered input tile
// (2x4x8 pooled outputs = 64 lanes; 6x10 rows x pitch 24 = 5.76KB/buf) and staged
// via global_load_lds width=16. The per-cin __syncthreads of r10 (which forced a
// block-wide s_waitcnt vmcnt(0) drain every K-step -- the guide's "barrier drain"
// stall; VALUBusy was 64%) is replaced by a wave-local counted wait:
//   issue 6 DMA for cin s+1  ->  s_waitcnt vmcnt(6)  (cin s landed, 6 in flight)
// vmcnt retires in issue order, so hoisted invariant loads only make the wait
// conservative, never unsafe. Only remaining block barriers: initial weight stage
// + CSPLIT partial-sum reduction (L3).
// HARD CONSTRAINTS (measured): G<=4 with r[64] (G=8 spills: r8 WRITE 964MB);
// launch_bounds must stay (TPB,2) (r6: bounds 3 -> VGPR 84 + spill);
// never split cin via global atomics (r5: 1.86GB HBM traffic).

#define GLOBAL_AS __attribute__((address_space(1)))
#define LDS_AS    __attribute__((address_space(3)))

static __device__ __forceinline__ void async_ld16(const float* g, float* l) {
    __builtin_amdgcn_global_load_lds((const GLOBAL_AS void*)g, (LDS_AS void*)l,
                                     16, 0, 0);
}

template <int TPB_, int CIN, int CSPLIT, int G,
          int WDT, int WHT, int WWT, int BD, int BH, int BW>
__global__ __launch_bounds__(TPB_, 2) void spline_block_kernel(
    const float* __restrict__ x,    // [N, CIN, D, H, W]
    const float* __restrict__ cw,   // [Cout, CIN, 27]
    const float* __restrict__ cb,   // [Cout]
    const float* __restrict__ knots,// [10]
    const float* __restrict__ sw,   // [Cout, 10]
    const float* __restrict__ w1,
    const float* __restrict__ w2,
    const float* __restrict__ g,
    const float* __restrict__ beta,
    const float* __restrict__ zbuf, // >=64B of zeros (16B aligned)
    float* __restrict__ out,        // [N, Cout, D/2, H/2, W/2]
    int N, int Cout, int D, int H, int W,
    int ntiles, int nthw, int ntw)
{
    constexpr int NSW    = BD * BH * BW;       // spatial wave-tiles per block
    constexpr int NW     = TPB_ / 64;          // waves per block
    constexpr int CPG    = CIN / CSPLIT;       // cins per cin-group (per wave set)
    constexpr int ID     = 2 * WDT + 2;        // input rows (d) per wave tile
    constexpr int IH     = 2 * WHT + 2;        // input rows (h) per wave tile
    constexpr int CHK    = (WWT + 4) / 2;      // 16B chunks per input row
    constexpr int PITCH  = CHK * 4;            // dwords per row
    constexpr int ROWS   = ID * IH;
    constexpr int CHUNKS = ROWS * CHK;
    constexpr int PHYS   = CHUNKS * 4;         // dwords per wave buffer
    constexpr int NCH    = (CHUNKS + 63) / 64; // DMA issues per cin per lane
    constexpr int BUFS   = (CPG > 1) ? 2 : 1;
    static_assert(NW == NSW * CSPLIT, "waves = spatial-tiles x cin-split");
    static_assert(WDT * WHT * WWT == 64, "one wave per spatial tile");
    static_assert(CIN % CSPLIT == 0, "cin divisible");
    static_assert(NCH <= 32, "mask fits u32");
    static_assert(NCH == 6, "s_waitcnt vmcnt(6) literal assumes 6 issues/cin");
    static_assert(CSPLIT == 1 ||
                  (CSPLIT - 1) * 64 * G * 8 <= NW * BUFS * PHYS,
                  "reduction scratch fits in tile");

    __shared__ __align__(16) float tile[NW][BUFS][PHYS];
    __shared__ float  wlds[CIN * G * 28];
    __shared__ float4 stbl[G * 11];            // spline prefix coeffs {A,3B,3C,D}

    const int PD = D >> 1, PH = H >> 1, PW = W >> 1;
    const int groups = Cout / G;
    const int tid  = threadIdx.x;
    const int wv   = tid >> 6;                 // wave id
    const int lane = tid & 63;
    const int sw_  = wv % NSW;                 // spatial wave-tile id
    const int cg   = wv / NSW;                 // cin-group id

    const int bx      = blockIdx.x;
    const int tile_id = bx % ntiles;
    const int t1      = bx / ntiles;
    const int grp     = t1 % groups;
    const int n       = t1 / groups;
    const int c0      = grp * G;
    const int cinbase = cg * CPG;

    const int td  = tile_id / nthw;
    const int rem = tile_id % nthw;
    const int th_ = rem / ntw;
    const int tw_ = rem % ntw;

    // stage weights + spline table (covered by the single initial barrier)
    for (int i = tid; i < CIN * G * 27; i += TPB_) {
        const int t  = i % 27;
        const int cgr = i / 27;
        const int gg = cgr % G;
        const int ci = cgr / G;
        wlds[cgr * 28 + t] = cw[((c0 + gg) * CIN + ci) * 27 + t];
    }
    for (int i = tid; i < G * 11; i += TPB_) {
        const int gg  = i / 11;
        const int cnt = i % 11;
        const int c   = c0 + gg;
        float A = 0.f, B3 = 0.f, C3 = 0.f, Dd = 0.f;
        for (int j = 0; j < cnt; j++) {
            const float s = sw[c * 10 + j];
            const float k = knots[j];
            A  += s;
            B3 += 3.0f * s * k;
            C3 += 3.0f * s * k * k;
            Dd += s * k * k * k;
        }
        stbl[i] = make_float4(A, B3, C3, Dd);
    }

    // wave spatial origin (pooled coords)
    const int swd = sw_ / (BH * BW);
    const int r2  = sw_ % (BH * BW);
    const int swh = r2 / BW;
    const int sww = r2 % BW;
    const int pd0 = td  * (BD * WDT) + swd * WDT;
    const int ph0 = th_ * (BH * WHT) + swh * WHT;
    const int pw0 = tw_ * (BW * WWT) + sww * WWT;

    const int pwl = lane % WWT;
    const int phl = (lane / WWT) % WHT;
    const int pdl = lane / (WWT * WHT);

    const int d0 = 2 * pd0 - 1, h0 = 2 * ph0 - 1;
    const int w0 = 2 * pw0 - 1;
    const int wb = w0 & ~3;                    // 4-dword aligned chunk origin
    const int woff = w0 - wb;                  // 1 or 3

    // per-chunk global offsets + validity (per wave tile, same for all cins)
    int off[NCH];
    unsigned vm = 0;
#pragma unroll
    for (int k = 0; k < NCH; k++) {
        const int chunk = lane + 64 * k;
        const int row = chunk / CHK, cs = chunk - row * CHK;
        const int dz = row / IH, hy = row - dz * IH;
        const int dd = d0 + dz, hh = h0 + hy;
        const int wsd = wb + cs * 4;
        const bool ok = (chunk < CHUNKS) &
                        ((unsigned)dd < (unsigned)D) &
                        ((unsigned)hh < (unsigned)H) &
                        ((unsigned)wsd < (unsigned)W);
        off[k] = ok ? (dd * H + hh) * W + wsd : 0;
        vm |= (unsigned)ok << k;
    }

    const size_t chstride = (size_t)D * H * W;
    const float* xn = x + (size_t)n * CIN * chstride;

    float acc[G][8];
#pragma unroll
    for (int gg = 0; gg < G; gg++)
#pragma unroll
        for (int i = 0; i < 8; i++) acc[gg][i] = 0.0f;

    __syncthreads();   // weights/table visible; vmcnt drained (clean slate)

    auto stage = [&](int ci, int buf) {
        const float* xc = xn + (size_t)ci * chstride;
        float* dst = &tile[wv][buf][0];
#pragma unroll
        for (int k = 0; k < NCH; k++) {
            const int chunk = lane + 64 * k;
            if ((k + 1) * 64 <= CHUNKS || chunk < CHUNKS) {
                const float* src = ((vm >> k) & 1) ? (xc + off[k]) : zbuf;
                async_ld16(src, dst + chunk * 4);
            }
        }
    };

    // prologue: each wave stages its first cin into its buf 0
    stage(cinbase, 0);

#pragma unroll 1
    for (int s = 0; s < CPG; s++) {
        const int cur = s & (BUFS - 1);
        if (s + 1 < CPG) {
            stage(cinbase + s + 1, cur ^ 1);   // 6 DMA issues, stay in flight
            asm volatile("s_waitcnt vmcnt(6)" ::: "memory");  // cin s landed
        } else {
            asm volatile("s_waitcnt vmcnt(0)" ::: "memory");
        }

        const int ci = cinbase + s;
        const float* tb = &tile[wv][cur][0];
        float r[64];
#pragma unroll
        for (int dz = 0; dz < 4; dz++)
#pragma unroll
        for (int dy = 0; dy < 4; dy++) {
            const int rb = ((2 * pdl + dz) * IH + (2 * phl + dy)) * PITCH +
                           woff + 2 * pwl;
            r[(dz * 4 + dy) * 4 + 0] = tb[rb + 0];
            r[(dz * 4 + dy) * 4 + 1] = tb[rb + 1];
            r[(dz * 4 + dy) * 4 + 2] = tb[rb + 2];
            r[(dz * 4 + dy) * 4 + 3] = tb[rb + 3];
        }

#pragma unroll
        for (int gg = 0; gg < G; gg++) {
            const float4* w4p = (const float4*)&wlds[(ci * G + gg) * 28];
#pragma unroll
            for (int ch = 0; ch < 7; ch++) {
                const float4 wv4 = w4p[ch];
#pragma unroll
                for (int j = 0; j < 4; j++) {
                    const int tap = ch * 4 + j;
                    if (tap < 27) {
                        const float wvj = (j == 0) ? wv4.x : (j == 1) ? wv4.y
                                        : (j == 2) ? wv4.z : wv4.w;
                        const int kd = tap / 9, kh = (tap % 9) / 3, kw = tap % 3;
#pragma unroll
                        for (int od = 0; od < 2; od++)
#pragma unroll
                        for (int oh = 0; oh < 2; oh++)
#pragma unroll
                        for (int ow = 0; ow < 2; ow++)
                            acc[gg][(od * 2 + oh) * 2 + ow] =
                                fmaf(wvj,
                                     r[((od + kd) * 4 + (oh + kh)) * 4 + (ow + kw)],
                                     acc[gg][(od * 2 + oh) * 2 + ow]);
                    }
                }
            }
        }
    }

    // combine partial accumulators across cin-groups (scratch aliases tile)
    float* af = &acc[0][0];
    if (CSPLIT > 1) {
        __syncthreads();                        // all waves done with their tiles
        float* scratch = &tile[0][0][0];
        if (cg > 0) {
#pragma unroll
            for (int idx = 0; idx < G * 8; idx++)
                scratch[(idx * (CSPLIT - 1) + (cg - 1)) * 64 + lane] = af[idx];
        }
        __syncthreads();
        if (cg == 0) {
#pragma unroll
            for (int idx = 0; idx < G * 8; idx++) {
                float s2 = af[idx];
                for (int j = 0; j < CSPLIT - 1; j++)
                    s2 += scratch[(idx * (CSPLIT - 1) + j) * 64 + lane];
                af[idx] = s2;
            }
        }
    }

    // epilogue (cin-group 0): bias + spline (prefix-Horner) + SiLU + BN + maxpool
    if (cg == 0) {
        const int pdg = pd0 + pdl, phg = ph0 + phl, pwg = pw0 + pwl;
#pragma unroll
        for (int gg = 0; gg < G; gg++) {
            const int c = c0 + gg;
            const float bias = cb[c];
            const float W1 = w1[c], W2 = w2[c];
            const float scale = g[c] * rsqrtf(1.0f + 1e-5f);
            const float bb = beta[c];

            float m = -INFINITY;
#pragma unroll
            for (int i = 0; i < 8; i++) {
                const float y = acc[gg][i] + bias;
                int idx = (int)floorf((y + 1.0f) * 4.5f) + 1;
                idx = min(max(idx, 0), 10);
                const float4 cf = stbl[gg * 11 + idx];
                const float sp = ((cf.x * y - cf.y) * y + cf.z) * y - cf.w;
                const float silu = y / (1.0f + __expf(-y));
                const float o = fmaf(W1 * sp + W2 * silu, scale, bb);
                m = fmaxf(m, o);
            }
            out[((size_t)(n * Cout + c) * PD + pdg) * PH * PW + phg * PW + pwg] = m;
        }
    }
}

// Global average pool: one wave per (n,c)
__global__ __launch_bounds__(64) void mean_kernel(
    const float* __restrict__ h, float* __restrict__ out, int S)
{
    const int nc = blockIdx.x;
    const int lane = threadIdx.x;
    const float* p = h + (size_t)nc * S;
    float s = 0.0f;
    for (int i = lane; i < S; i += 64) s += p[i];
#pragma unroll
    for (int off = 32; off > 0; off >>= 1) s += __shfl_down(s, off, 64);
    if (lane == 0) out[nc] = s / (float)S;
}

// fc1(128->256)+ReLU then fc2(256->2), batch 2
__global__ __launch_bounds__(256) void fc_kernel(
    const float* __restrict__ pooled,
    const float* __restrict__ w1, const float* __restrict__ b1,
    const float* __restrict__ w2, const float* __restrict__ b2,
    float* __restrict__ out)
{
    __shared__ float hbuf[2][256];
    const int j = threadIdx.x;
#pragma unroll
    for (int nn = 0; nn < 2; nn++) {
        float s = b1[j];
        for (int k = 0; k < 128; k++)
            s = fmaf(pooled[nn * 128 + k], w1[j * 128 + k], s);
        hbuf[nn][j] = fmaxf(s, 0.0f);
    }
    __syncthreads();
    const int wid = j >> 6, lane = j & 63;
    const int nn = wid >> 1, oo = wid & 1;
    float s = 0.0f;
    for (int k = lane; k < 256; k += 64) s += hbuf[nn][k] * w2[oo * 256 + k];
#pragma unroll
    for (int off = 32; off > 0; off >>= 1) s += __shfl_down(s, off, 64);
    if (lane == 0) out[nn * 2 + oo] = s + b2[oo];
}

extern "C" void kernel_launch(void* const* d_in, const int* in_sizes, int n_in,
                              void* d_out, int out_size, void* d_ws, size_t ws_size,
                              hipStream_t stream) {
    const float* x      = (const float*)d_in[0];
    const float* c1_w   = (const float*)d_in[1];
    const float* c1_b   = (const float*)d_in[2];
    const float* c1_kn  = (const float*)d_in[3];
    const float* c1_sw  = (const float*)d_in[4];
    const float* c1_w1  = (const float*)d_in[5];
    const float* c1_w2  = (const float*)d_in[6];
    const float* bn1_g  = (const float*)d_in[7];
    const float* bn1_b  = (const float*)d_in[8];
    const float* c2_w   = (const float*)d_in[9];
    const float* c2_b   = (const float*)d_in[10];
    const float* c2_kn  = (const float*)d_in[11];
    const float* c2_sw  = (const float*)d_in[12];
    const float* c2_w1  = (const float*)d_in[13];
    const float* c2_w2  = (const float*)d_in[14];
    const float* bn2_g  = (const float*)d_in[15];
    const float* bn2_b  = (const float*)d_in[16];
    const float* c3_w   = (const float*)d_in[17];
    const float* c3_b   = (const float*)d_in[18];
    const float* c3_kn  = (const float*)d_in[19];
    const float* c3_sw  = (const float*)d_in[20];
    const float* c3_w1  = (const float*)d_in[21];
    const float* c3_w2  = (const float*)d_in[22];
    const float* bn3_g  = (const float*)d_in[23];
    const float* bn3_b  = (const float*)d_in[24];
    const float* fc1_w  = (const float*)d_in[25];
    const float* fc1_b  = (const float*)d_in[26];
    const float* fc2_w  = (const float*)d_in[27];
    const float* fc2_b  = (const float*)d_in[28];

    float* ws = (float*)d_ws;
    float* h1     = ws;                  // 2*32*32^3 = 2,097,152 fl
    float* h2     = h1 + 2097152;        // 2*64*16^3 =   524,288 fl
    float* h3     = h2 + 524288;         // 2*128*8^3 =   131,072 fl
    float* pooled = h3 + 131072;         // 256 fl
    float* zbuf   = pooled + 256;        // 64 B zeros (16B aligned)

    hipMemsetAsync(zbuf, 0, 64, stream);

    // All layers: wave tile 2x4x8 (ID=6, IH=10, PITCH=24, 6 DMA issues/cin).
    // L1: (2,1,64^3)->(2,32,32^3). 4 spatial waves (2x2x1) -> block tile 4x8x8.
    // LDS ~24KB. grid = 2*8*128 = 2048 of 256.
    spline_block_kernel<256, 1, 1, 4, 2, 4, 8, 2, 2, 1>
        <<<dim3(2048), dim3(256), 0, stream>>>(
        x, c1_w, c1_b, c1_kn, c1_sw, c1_w1, c1_w2, bn1_g, bn1_b, zbuf, h1,
        2, 32, 64, 64, 64, 128, 16, 4);
    // L2: (2,32,32^3)->(2,64,16^3). 4 spatial waves -> block tile 4x8x8.
    // LDS ~61KB -> 2 blocks/CU. grid = 2*16*16 = 512 of 256. Barrier-free K-loop.
    spline_block_kernel<256, 32, 1, 4, 2, 4, 8, 2, 2, 1>
        <<<dim3(512), dim3(256), 0, stream>>>(
        h1, c2_w, c2_b, c2_kn, c2_sw, c2_w1, c2_w2, bn2_g, bn2_b, zbuf, h2,
        2, 64, 32, 32, 32, 16, 4, 2);
    // L3: (2,64,16^3)->(2,128,8^3). CSPLIT=4: 4 waves share one spatial tile,
    // 16 cins each, private tiles, LDS reduction at end. LDS ~75KB -> 2 blocks/CU.
    // grid = 2*32*8 = 512 of 256.
    spline_block_kernel<256, 64, 4, 4, 2, 4, 8, 1, 1, 1>
        <<<dim3(512), dim3(256), 0, stream>>>(
        h2, c3_w, c3_b, c3_kn, c3_sw, c3_w1, c3_w2, bn3_g, bn3_b, zbuf, h3,
        2, 128, 16, 16, 16, 8, 2, 1);
    // head
    mean_kernel<<<dim3(256), dim3(64), 0, stream>>>(h3, pooled, 512);
    fc_kernel<<<dim3(1), dim3(256), 0, stream>>>(pooled, fc1_w, fc1_b, fc2_w, fc2_b,
                                                 (float*)d_out);
}